// Round 1
// baseline (849.546 us; speedup 1.0000x reference)
//
#include <hip/hip_runtime.h>

// Problem constants (match reference)
#define NN 50000
#define NE 800000

// ---------------------------------------------------------------------------
// Layer-1 edge scatter: S1[d] += x[s] (64f), EA[d] += ea[e] (32f), cnt[d] += 1
// One 64-lane wave per edge.
// ---------------------------------------------------------------------------
__global__ void scatter1_kernel(const float* __restrict__ x,
                                const float* __restrict__ ea,
                                const int* __restrict__ src,
                                const int* __restrict__ dst,
                                float* __restrict__ S1,
                                float* __restrict__ EA,
                                float* __restrict__ cnt,
                                int E)
{
    int tid  = blockIdx.x * blockDim.x + threadIdx.x;
    int wid  = tid >> 6;
    int lane = threadIdx.x & 63;
    int nw   = (gridDim.x * blockDim.x) >> 6;
    for (int e = wid; e < E; e += nw) {
        int s = src[e];
        int d = dst[e];
        atomicAdd(&S1[d * 64 + lane], x[s * 64 + lane]);
        if (lane < 32) {
            atomicAdd(&EA[d * 32 + lane], ea[e * 32 + lane]);
        } else if (lane == 32) {
            atomicAdd(&cnt[d], 1.0f);
        }
    }
}

// ---------------------------------------------------------------------------
// Layer-2 edge scatter: S2[d] += h1[s] (128f). One wave per edge, 2 feats/lane.
// ---------------------------------------------------------------------------
__global__ void scatter2_kernel(const float* __restrict__ h1,
                                const int* __restrict__ src,
                                const int* __restrict__ dst,
                                float* __restrict__ S2,
                                int E)
{
    int tid  = blockIdx.x * blockDim.x + threadIdx.x;
    int wid  = tid >> 6;
    int lane = threadIdx.x & 63;
    int nw   = (gridDim.x * blockDim.x) >> 6;
    for (int e = wid; e < E; e += nw) {
        int s = src[e];
        int d = dst[e];
        atomicAdd(&S2[d * 128 + lane],      h1[s * 128 + lane]);
        atomicAdd(&S2[d * 128 + 64 + lane], h1[s * 128 + 64 + lane]);
    }
}

// ---------------------------------------------------------------------------
// Layer-1 node kernel: aggr = (S1@Wmx + EA@Wme + cnt*b_msg)/max(cnt,1)
//                      h1   = relu([x, aggr] @ W_app + b_app)
// Block: 128 threads (one per output feature), 16 nodes per block.
// ---------------------------------------------------------------------------
#define NPB1 16
__global__ __launch_bounds__(128) void node1_kernel(
    const float* __restrict__ x,
    const float* __restrict__ S1,
    const float* __restrict__ EA,
    const float* __restrict__ cnt,
    const float* __restrict__ Wmsg,   // [96][128] rows: 0-63 x-part, 64-95 ea-part
    const float* __restrict__ bmsg,   // [128]
    const float* __restrict__ Wapp,   // [192][128] rows: 0-63 x, 64-191 aggr
    const float* __restrict__ bapp,   // [128]
    float* __restrict__ h1,
    int N)
{
    __shared__ float sF[NPB1][96];    // [S1 | EA] per node
    __shared__ float sX[NPB1][64];
    __shared__ float sAgg[NPB1][128];
    __shared__ float sCnt[NPB1];

    int j = threadIdx.x;              // 0..127
    int base = blockIdx.x * NPB1;

    for (int t = j; t < NPB1 * 64; t += 128) {
        int n = t >> 6, k = t & 63;
        int v = base + n;
        sF[n][k] = (v < N) ? S1[v * 64 + k] : 0.f;
        sX[n][k] = (v < N) ? x[v * 64 + k] : 0.f;
    }
    for (int t = j; t < NPB1 * 32; t += 128) {
        int n = t >> 5, k = t & 31;
        int v = base + n;
        sF[n][64 + k] = (v < N) ? EA[v * 32 + k] : 0.f;
    }
    if (j < NPB1) {
        int v = base + j;
        sCnt[j] = (v < N) ? cnt[v] : 0.f;
    }
    __syncthreads();

    float acc[NPB1];
#pragma unroll
    for (int n = 0; n < NPB1; n++) acc[n] = 0.f;

    for (int k = 0; k < 96; k++) {
        float w = Wmsg[k * 128 + j];
#pragma unroll
        for (int n = 0; n < NPB1; n++) acc[n] += sF[n][k] * w;
    }
    float bm = bmsg[j];
#pragma unroll
    for (int n = 0; n < NPB1; n++) {
        float c = sCnt[n];
        sAgg[n][j] = (acc[n] + c * bm) / fmaxf(c, 1.0f);
    }
    __syncthreads();

#pragma unroll
    for (int n = 0; n < NPB1; n++) acc[n] = 0.f;
    for (int k = 0; k < 64; k++) {
        float w = Wapp[k * 128 + j];
#pragma unroll
        for (int n = 0; n < NPB1; n++) acc[n] += sX[n][k] * w;
    }
    for (int k = 0; k < 128; k++) {
        float w = Wapp[(64 + k) * 128 + j];
#pragma unroll
        for (int n = 0; n < NPB1; n++) acc[n] += sAgg[n][k] * w;
    }
    float ba = bapp[j];
#pragma unroll
    for (int n = 0; n < NPB1; n++) {
        int v = base + n;
        if (v < N) h1[v * 128 + j] = fmaxf(acc[n] + ba, 0.f);
    }
}

// ---------------------------------------------------------------------------
// Layer-2 node kernel: aggr2 = (S2@Wmx + EA@Wme + cnt*b_msg2)/max(cnt,1)
//                      out   = relu([h1, aggr2] @ W_app2 + b_app2)
// Block: 64 threads (one per output feature), 16 nodes per block.
// ---------------------------------------------------------------------------
#define NPB2 16
__global__ __launch_bounds__(64) void node2_kernel(
    const float* __restrict__ h1,
    const float* __restrict__ S2,
    const float* __restrict__ EA,
    const float* __restrict__ cnt,
    const float* __restrict__ Wmsg,   // [160][64] rows: 0-127 h-part, 128-159 ea-part
    const float* __restrict__ bmsg,   // [64]
    const float* __restrict__ Wapp,   // [192][64] rows: 0-127 h, 128-191 aggr
    const float* __restrict__ bapp,   // [64]
    float* __restrict__ out,
    int N)
{
    __shared__ float sF[NPB2][160];   // [S2 | EA] per node
    __shared__ float sH[NPB2][128];
    __shared__ float sAgg[NPB2][64];
    __shared__ float sCnt[NPB2];

    int j = threadIdx.x;              // 0..63
    int base = blockIdx.x * NPB2;

    for (int t = j; t < NPB2 * 128; t += 64) {
        int n = t >> 7, k = t & 127;
        int v = base + n;
        sF[n][k] = (v < N) ? S2[v * 128 + k] : 0.f;
        sH[n][k] = (v < N) ? h1[v * 128 + k] : 0.f;
    }
    for (int t = j; t < NPB2 * 32; t += 64) {
        int n = t >> 5, k = t & 31;
        int v = base + n;
        sF[n][128 + k] = (v < N) ? EA[v * 32 + k] : 0.f;
    }
    if (j < NPB2) {
        int v = base + j;
        sCnt[j] = (v < N) ? cnt[v] : 0.f;
    }
    __syncthreads();

    float acc[NPB2];
#pragma unroll
    for (int n = 0; n < NPB2; n++) acc[n] = 0.f;

    for (int k = 0; k < 160; k++) {
        float w = Wmsg[k * 64 + j];
#pragma unroll
        for (int n = 0; n < NPB2; n++) acc[n] += sF[n][k] * w;
    }
    float bm = bmsg[j];
#pragma unroll
    for (int n = 0; n < NPB2; n++) {
        float c = sCnt[n];
        sAgg[n][j] = (acc[n] + c * bm) / fmaxf(c, 1.0f);
    }
    __syncthreads();

#pragma unroll
    for (int n = 0; n < NPB2; n++) acc[n] = 0.f;
    for (int k = 0; k < 128; k++) {
        float w = Wapp[k * 64 + j];
#pragma unroll
        for (int n = 0; n < NPB2; n++) acc[n] += sH[n][k] * w;
    }
    for (int k = 0; k < 64; k++) {
        float w = Wapp[(128 + k) * 64 + j];
#pragma unroll
        for (int n = 0; n < NPB2; n++) acc[n] += sAgg[n][k] * w;
    }
    float ba = bapp[j];
#pragma unroll
    for (int n = 0; n < NPB2; n++) {
        int v = base + n;
        if (v < N) out[v * 64 + j] = fmaxf(acc[n] + ba, 0.f);
    }
}

// ---------------------------------------------------------------------------
extern "C" void kernel_launch(void* const* d_in, const int* in_sizes, int n_in,
                              void* d_out, int out_size, void* d_ws, size_t ws_size,
                              hipStream_t stream) {
    const float* x      = (const float*)d_in[0];
    const int*   ei     = (const int*)d_in[1];
    const float* ea     = (const float*)d_in[2];
    const float* Wmsg1  = (const float*)d_in[3];
    const float* bmsg1  = (const float*)d_in[4];
    const float* Wapp1  = (const float*)d_in[5];
    const float* bapp1  = (const float*)d_in[6];
    const float* Wmsg2  = (const float*)d_in[7];
    const float* bmsg2  = (const float*)d_in[8];
    const float* Wapp2  = (const float*)d_in[9];
    const float* bapp2  = (const float*)d_in[10];

    const int N = in_sizes[0] / 64;      // 50000
    const int E = in_sizes[1] / 2;       // 800000
    const int* src = ei;
    const int* dst = ei + E;

    // Workspace layout (floats):
    //  [cnt N][S1 N*64][EA N*32][S2 N*128]  <- zeroed each call (atomics)
    //  [h1 N*128]                           <- fully overwritten
    float* ws  = (float*)d_ws;
    float* cnt = ws;
    float* S1  = cnt + N;
    float* EA  = S1 + (size_t)N * 64;
    float* S2  = EA + (size_t)N * 32;
    float* h1  = S2 + (size_t)N * 128;

    size_t zero_bytes = (size_t)N * (1 + 64 + 32 + 128) * sizeof(float);
    hipMemsetAsync(d_ws, 0, zero_bytes, stream);

    // Layer 1 scatter
    {
        dim3 grid(2048), block(256);
        scatter1_kernel<<<grid, block, 0, stream>>>(x, ea, src, dst, S1, EA, cnt, E);
    }
    // Layer 1 node GEMMs
    {
        int blocks = (N + NPB1 - 1) / NPB1;
        node1_kernel<<<blocks, 128, 0, stream>>>(x, S1, EA, cnt,
                                                 Wmsg1, bmsg1, Wapp1, bapp1, h1, N);
    }
    // Layer 2 scatter
    {
        dim3 grid(2048), block(256);
        scatter2_kernel<<<grid, block, 0, stream>>>(h1, src, dst, S2, E);
    }
    // Layer 2 node GEMMs
    {
        int blocks = (N + NPB2 - 1) / NPB2;
        node2_kernel<<<blocks, 64, 0, stream>>>(h1, S2, EA, cnt,
                                                Wmsg2, bmsg2, Wapp2, bapp2,
                                                (float*)d_out, N);
    }
}

// Round 2
// 575.430 us; speedup vs baseline: 1.4764x; 1.4764x over previous
//
#include <hip/hip_runtime.h>

#define SCAN_CHUNK 1024

// ---------------------------------------------------------------------------
// CSR build: degree histogram
// ---------------------------------------------------------------------------
__global__ void hist_kernel(const int* __restrict__ dst, int* __restrict__ deg, int E)
{
    int e = blockIdx.x * blockDim.x + threadIdx.x;
    if (e < E) atomicAdd(&deg[dst[e]], 1);
}

// Per-chunk partial sums (one block of 256 per 1024-chunk)
__global__ __launch_bounds__(256) void scanA_kernel(const int* __restrict__ deg,
                                                    int* __restrict__ part, int N)
{
    __shared__ int red[256];
    int b = blockIdx.x, t = threadIdx.x;
    int base = b * SCAN_CHUNK;
    int s = 0;
    for (int i = t; i < SCAN_CHUNK; i += 256) {
        int idx = base + i;
        s += (idx < N) ? deg[idx] : 0;
    }
    red[t] = s;
    __syncthreads();
    for (int o = 128; o > 0; o >>= 1) {
        if (t < o) red[t] += red[t + o];
        __syncthreads();
    }
    if (t == 0) part[b] = red[0];
}

// Exclusive scan of chunk partials (NCH <= 64, single wave)
__global__ void scanB_kernel(int* __restrict__ part, int* __restrict__ offN, int NCH)
{
    int lane = threadIdx.x;
    int orig = (lane < NCH) ? part[lane] : 0;
    int v = orig;
    for (int s = 1; s < 64; s <<= 1) {
        int t = __shfl_up(v, s);
        if (lane >= s) v += t;
    }
    if (lane < NCH) part[lane] = v - orig;
    if (lane == NCH - 1) *offN = v;
}

// Per-chunk inclusive scan -> global exclusive offsets + cursor copy
__global__ __launch_bounds__(SCAN_CHUNK) void scanC_kernel(const int* __restrict__ deg,
                                                           const int* __restrict__ part,
                                                           int* __restrict__ off,
                                                           int* __restrict__ cursor, int N)
{
    __shared__ int buf[SCAN_CHUNK];
    int b = blockIdx.x, t = threadIdx.x;
    int idx = b * SCAN_CHUNK + t;
    int v = (idx < N) ? deg[idx] : 0;
    buf[t] = v;
    __syncthreads();
    for (int s = 1; s < SCAN_CHUNK; s <<= 1) {
        int tmp = (t >= s) ? buf[t - s] : 0;
        __syncthreads();
        buf[t] += tmp;
        __syncthreads();
    }
    int excl = buf[t] - v + part[b];
    if (idx < N) { off[idx] = excl; cursor[idx] = excl; }
}

// Fill edge list grouped by dst: elist[p] = (src, edge_id)
__global__ void fill_kernel(const int* __restrict__ src, const int* __restrict__ dst,
                            int* __restrict__ cursor, int2* __restrict__ elist, int E)
{
    int e = blockIdx.x * blockDim.x + threadIdx.x;
    if (e >= E) return;
    int d = dst[e];
    int p = atomicAdd(&cursor[d], 1);
    elist[p] = make_int2(src[e], e);
}

// ---------------------------------------------------------------------------
// Layer-1 aggregate: one wave per node. S1[v] = sum x[src], EA[v] = sum ea[e]
// ---------------------------------------------------------------------------
__global__ __launch_bounds__(256) void agg1_kernel(const float* __restrict__ x,
                                                   const float* __restrict__ ea,
                                                   const int2* __restrict__ elist,
                                                   const int* __restrict__ off,
                                                   float* __restrict__ S1,
                                                   float* __restrict__ EA, int N)
{
    int wv = (blockIdx.x * blockDim.x + threadIdx.x) >> 6;
    int lane = threadIdx.x & 63;
    if (wv >= N) return;
    int beg = off[wv], end = off[wv + 1];
    float sx = 0.f, se = 0.f;
    for (int i = beg; i < end; i++) {
        int2 p = elist[i];
        sx += x[(size_t)p.x * 64 + lane];
        if (lane < 32) se += ea[(size_t)p.y * 32 + lane];
    }
    S1[(size_t)wv * 64 + lane] = sx;
    if (lane < 32) EA[(size_t)wv * 32 + lane] = se;
}

// ---------------------------------------------------------------------------
// Layer-2 aggregate: one wave per node. S2g[v] = sum g2[src] (64f)
// ---------------------------------------------------------------------------
__global__ __launch_bounds__(256) void agg2_kernel(const float* __restrict__ g2,
                                                   const int2* __restrict__ elist,
                                                   const int* __restrict__ off,
                                                   float* __restrict__ S2g, int N)
{
    int wv = (blockIdx.x * blockDim.x + threadIdx.x) >> 6;
    int lane = threadIdx.x & 63;
    if (wv >= N) return;
    int beg = off[wv], end = off[wv + 1];
    float sg = 0.f;
    for (int i = beg; i < end; i++) {
        int2 p = elist[i];
        sg += g2[(size_t)p.x * 64 + lane];
    }
    S2g[(size_t)wv * 64 + lane] = sg;
}

// ---------------------------------------------------------------------------
// Layer-1 node kernel + fused g2 = h1 @ Wmsg2[0:128]
// ---------------------------------------------------------------------------
#define NPB1 16
__global__ __launch_bounds__(128) void node1_kernel(
    const float* __restrict__ x,
    const float* __restrict__ S1,
    const float* __restrict__ EA,
    const int*   __restrict__ deg,
    const float* __restrict__ Wmsg,   // [96][128] rows: 0-63 x-part, 64-95 ea-part
    const float* __restrict__ bmsg,   // [128]
    const float* __restrict__ Wapp,   // [192][128] rows: 0-63 x, 64-191 aggr
    const float* __restrict__ bapp,   // [128]
    const float* __restrict__ Wm2h,   // Wmsg2 rows 0..127 -> [128][64]
    float* __restrict__ h1,
    float* __restrict__ g2,
    int N)
{
    __shared__ float sF[NPB1][96];    // [S1 | EA] per node
    __shared__ float sX[NPB1][64];
    __shared__ float sAgg[NPB1][128];
    __shared__ float sH[NPB1][128];
    __shared__ float sCnt[NPB1];

    int j = threadIdx.x;              // 0..127
    int base = blockIdx.x * NPB1;

    for (int t = j; t < NPB1 * 64; t += 128) {
        int n = t >> 6, k = t & 63;
        int v = base + n;
        sF[n][k] = (v < N) ? S1[(size_t)v * 64 + k] : 0.f;
        sX[n][k] = (v < N) ? x[(size_t)v * 64 + k] : 0.f;
    }
    for (int t = j; t < NPB1 * 32; t += 128) {
        int n = t >> 5, k = t & 31;
        int v = base + n;
        sF[n][64 + k] = (v < N) ? EA[(size_t)v * 32 + k] : 0.f;
    }
    if (j < NPB1) {
        int v = base + j;
        sCnt[j] = (v < N) ? (float)deg[v] : 0.f;
    }
    __syncthreads();

    float acc[NPB1];
#pragma unroll
    for (int n = 0; n < NPB1; n++) acc[n] = 0.f;

    for (int k = 0; k < 96; k++) {
        float w = Wmsg[k * 128 + j];
#pragma unroll
        for (int n = 0; n < NPB1; n++) acc[n] += sF[n][k] * w;
    }
    float bm = bmsg[j];
#pragma unroll
    for (int n = 0; n < NPB1; n++) {
        float c = sCnt[n];
        sAgg[n][j] = (acc[n] + c * bm) / fmaxf(c, 1.0f);
    }
    __syncthreads();

#pragma unroll
    for (int n = 0; n < NPB1; n++) acc[n] = 0.f;
    for (int k = 0; k < 64; k++) {
        float w = Wapp[k * 128 + j];
#pragma unroll
        for (int n = 0; n < NPB1; n++) acc[n] += sX[n][k] * w;
    }
    for (int k = 0; k < 128; k++) {
        float w = Wapp[(64 + k) * 128 + j];
#pragma unroll
        for (int n = 0; n < NPB1; n++) acc[n] += sAgg[n][k] * w;
    }
    float ba = bapp[j];
#pragma unroll
    for (int n = 0; n < NPB1; n++) {
        float hv = fmaxf(acc[n] + ba, 0.f);
        sH[n][j] = hv;
        int v = base + n;
        if (v < N) h1[(size_t)v * 128 + j] = hv;
    }
    __syncthreads();

    // g2 = h1 @ Wm2h  (128 -> 64). threads j<64: nodes 0..7; j>=64: nodes 8..15
    int col = j & 63;
    int nb = (j >> 6) * 8;
    float ga[8];
#pragma unroll
    for (int n = 0; n < 8; n++) ga[n] = 0.f;
    for (int k = 0; k < 128; k++) {
        float w = Wm2h[k * 64 + col];
#pragma unroll
        for (int n = 0; n < 8; n++) ga[n] += sH[nb + n][k] * w;
    }
#pragma unroll
    for (int n = 0; n < 8; n++) {
        int v = base + nb + n;
        if (v < N) g2[(size_t)v * 64 + col] = ga[n];
    }
}

// ---------------------------------------------------------------------------
// Layer-2 node kernel: aggr2 = (S2g + EA@We2 + cnt*b_msg2)/max(cnt,1)
//                      out   = relu([h1, aggr2] @ W_app2 + b_app2)
// ---------------------------------------------------------------------------
#define NPB2 16
__global__ __launch_bounds__(64) void node2_kernel(
    const float* __restrict__ h1,
    const float* __restrict__ S2g,
    const float* __restrict__ EA,
    const int*   __restrict__ deg,
    const float* __restrict__ Wme,    // Wmsg2 rows 128..159 -> [32][64]
    const float* __restrict__ bmsg,   // [64]
    const float* __restrict__ Wapp,   // [192][64] rows: 0-127 h, 128-191 aggr
    const float* __restrict__ bapp,   // [64]
    float* __restrict__ out,
    int N)
{
    __shared__ float sEA[NPB2][32];
    __shared__ float sH[NPB2][128];
    __shared__ float sAgg[NPB2][64];
    __shared__ float sCnt[NPB2];

    int j = threadIdx.x;              // 0..63
    int base = blockIdx.x * NPB2;

    for (int t = j; t < NPB2 * 128; t += 64) {
        int n = t >> 7, k = t & 127;
        int v = base + n;
        sH[n][k] = (v < N) ? h1[(size_t)v * 128 + k] : 0.f;
    }
    for (int t = j; t < NPB2 * 32; t += 64) {
        int n = t >> 5, k = t & 31;
        int v = base + n;
        sEA[n][k] = (v < N) ? EA[(size_t)v * 32 + k] : 0.f;
    }
    if (j < NPB2) {
        int v = base + j;
        sCnt[j] = (v < N) ? (float)deg[v] : 0.f;
    }
    __syncthreads();

    float acc[NPB2];
#pragma unroll
    for (int n = 0; n < NPB2; n++) acc[n] = 0.f;

    for (int k = 0; k < 32; k++) {
        float w = Wme[k * 64 + j];
#pragma unroll
        for (int n = 0; n < NPB2; n++) acc[n] += sEA[n][k] * w;
    }
    float bm = bmsg[j];
#pragma unroll
    for (int n = 0; n < NPB2; n++) {
        int v = base + n;
        float sg = (v < N) ? S2g[(size_t)v * 64 + j] : 0.f;
        float c = sCnt[n];
        sAgg[n][j] = (sg + acc[n] + c * bm) / fmaxf(c, 1.0f);
    }
    __syncthreads();

#pragma unroll
    for (int n = 0; n < NPB2; n++) acc[n] = 0.f;
    for (int k = 0; k < 128; k++) {
        float w = Wapp[k * 64 + j];
#pragma unroll
        for (int n = 0; n < NPB2; n++) acc[n] += sH[n][k] * w;
    }
    for (int k = 0; k < 64; k++) {
        float w = Wapp[(128 + k) * 64 + j];
#pragma unroll
        for (int n = 0; n < NPB2; n++) acc[n] += sAgg[n][k] * w;
    }
    float ba = bapp[j];
#pragma unroll
    for (int n = 0; n < NPB2; n++) {
        int v = base + n;
        if (v < N) out[(size_t)v * 64 + j] = fmaxf(acc[n] + ba, 0.f);
    }
}

// ---------------------------------------------------------------------------
extern "C" void kernel_launch(void* const* d_in, const int* in_sizes, int n_in,
                              void* d_out, int out_size, void* d_ws, size_t ws_size,
                              hipStream_t stream) {
    const float* x      = (const float*)d_in[0];
    const int*   ei     = (const int*)d_in[1];
    const float* ea     = (const float*)d_in[2];
    const float* Wmsg1  = (const float*)d_in[3];
    const float* bmsg1  = (const float*)d_in[4];
    const float* Wapp1  = (const float*)d_in[5];
    const float* bapp1  = (const float*)d_in[6];
    const float* Wmsg2  = (const float*)d_in[7];
    const float* bmsg2  = (const float*)d_in[8];
    const float* Wapp2  = (const float*)d_in[9];
    const float* bapp2  = (const float*)d_in[10];

    const int N = in_sizes[0] / 64;      // 50000
    const int E = in_sizes[1] / 2;       // 800000
    const int NCH = (N + SCAN_CHUNK - 1) / SCAN_CHUNK;   // 49
    const int* src = ei;
    const int* dst = ei + E;

    // Workspace layout (256B-aligned slices)
    uint8_t* p = (uint8_t*)d_ws;
    auto alloc = [&](size_t bytes) -> void* {
        void* r = (void*)p;
        p += (bytes + 255) & ~(size_t)255;
        return r;
    };
    int*   deg    = (int*)alloc((size_t)N * 4);
    int*   off    = (int*)alloc((size_t)(N + 1) * 4);
    int*   cursor = (int*)alloc((size_t)N * 4);
    int*   part   = (int*)alloc((size_t)NCH * 4);
    int2*  elist  = (int2*)alloc((size_t)E * 8);
    float* S1     = (float*)alloc((size_t)N * 64 * 4);  // reused as S2g
    float* EA     = (float*)alloc((size_t)N * 32 * 4);
    float* h1     = (float*)alloc((size_t)N * 128 * 4);
    float* g2     = (float*)alloc((size_t)N * 64 * 4);
    float* S2g    = S1;   // safe: S1 consumed by node1 before agg2 writes S2g

    hipMemsetAsync(deg, 0, (size_t)N * 4, stream);

    // CSR build
    hist_kernel<<<(E + 255) / 256, 256, 0, stream>>>(dst, deg, E);
    scanA_kernel<<<NCH, 256, 0, stream>>>(deg, part, N);
    scanB_kernel<<<1, 64, 0, stream>>>(part, off + N, NCH);
    scanC_kernel<<<NCH, SCAN_CHUNK, 0, stream>>>(deg, part, off, cursor, N);
    fill_kernel<<<(E + 255) / 256, 256, 0, stream>>>(src, dst, cursor, elist, E);

    // Layer 1
    agg1_kernel<<<(N + 3) / 4, 256, 0, stream>>>(x, ea, elist, off, S1, EA, N);
    node1_kernel<<<(N + NPB1 - 1) / NPB1, 128, 0, stream>>>(
        x, S1, EA, deg, Wmsg1, bmsg1, Wapp1, bapp1, Wmsg2 /*rows 0..127*/,
        h1, g2, N);

    // Layer 2
    agg2_kernel<<<(N + 3) / 4, 256, 0, stream>>>(g2, elist, off, S2g, N);
    node2_kernel<<<(N + NPB2 - 1) / NPB2, 64, 0, stream>>>(
        h1, S2g, EA, deg, Wmsg2 + 128 * 64, bmsg2, Wapp2, bapp2,
        (float*)d_out, N);
}

// Round 3
// 462.438 us; speedup vs baseline: 1.8371x; 1.2443x over previous
//
#include <hip/hip_runtime.h>

#define SCAN_CHUNK 1024

// ---------------------------------------------------------------------------
// CSR build: degree histogram
// ---------------------------------------------------------------------------
__global__ void hist_kernel(const int* __restrict__ dst, int* __restrict__ deg, int E)
{
    int e = blockIdx.x * blockDim.x + threadIdx.x;
    if (e < E) atomicAdd(&deg[dst[e]], 1);
}

// Per-chunk partial sums (one block of 256 per 1024-chunk)
__global__ __launch_bounds__(256) void scanA_kernel(const int* __restrict__ deg,
                                                    int* __restrict__ part, int N)
{
    __shared__ int red[256];
    int b = blockIdx.x, t = threadIdx.x;
    int base = b * SCAN_CHUNK;
    int s = 0;
    for (int i = t; i < SCAN_CHUNK; i += 256) {
        int idx = base + i;
        s += (idx < N) ? deg[idx] : 0;
    }
    red[t] = s;
    __syncthreads();
    for (int o = 128; o > 0; o >>= 1) {
        if (t < o) red[t] += red[t + o];
        __syncthreads();
    }
    if (t == 0) part[b] = red[0];
}

// Exclusive scan of chunk partials (NCH <= 64, single wave)
__global__ void scanB_kernel(int* __restrict__ part, int* __restrict__ offN, int NCH)
{
    int lane = threadIdx.x;
    int orig = (lane < NCH) ? part[lane] : 0;
    int v = orig;
    for (int s = 1; s < 64; s <<= 1) {
        int t = __shfl_up(v, s);
        if (lane >= s) v += t;
    }
    if (lane < NCH) part[lane] = v - orig;
    if (lane == NCH - 1) *offN = v;
}

// Per-chunk inclusive scan -> global exclusive offsets + cursor copy
__global__ __launch_bounds__(SCAN_CHUNK) void scanC_kernel(const int* __restrict__ deg,
                                                           const int* __restrict__ part,
                                                           int* __restrict__ off,
                                                           int* __restrict__ cursor, int N)
{
    __shared__ int buf[SCAN_CHUNK];
    int b = blockIdx.x, t = threadIdx.x;
    int idx = b * SCAN_CHUNK + t;
    int v = (idx < N) ? deg[idx] : 0;
    buf[t] = v;
    __syncthreads();
    for (int s = 1; s < SCAN_CHUNK; s <<= 1) {
        int tmp = (t >= s) ? buf[t - s] : 0;
        __syncthreads();
        buf[t] += tmp;
        __syncthreads();
    }
    int excl = buf[t] - v + part[b];
    if (idx < N) { off[idx] = excl; cursor[idx] = excl; }
}

// Fill edge list grouped by dst: elist[p] = (src, edge_id)
__global__ void fill_kernel(const int* __restrict__ src, const int* __restrict__ dst,
                            int* __restrict__ cursor, int2* __restrict__ elist, int E)
{
    int e = blockIdx.x * blockDim.x + threadIdx.x;
    if (e >= E) return;
    int d = dst[e];
    int p = atomicAdd(&cursor[d], 1);
    elist[p] = make_int2(src[e], e);
}

// ---------------------------------------------------------------------------
// Layer-1 aggregate: one wave per node, 4-way unrolled gather.
// ---------------------------------------------------------------------------
__global__ __launch_bounds__(256) void agg1_kernel(const float* __restrict__ x,
                                                   const float* __restrict__ ea,
                                                   const int2* __restrict__ elist,
                                                   const int* __restrict__ off,
                                                   float* __restrict__ S1,
                                                   float* __restrict__ EA, int N)
{
    int wv = (blockIdx.x * blockDim.x + threadIdx.x) >> 6;
    int lane = threadIdx.x & 63;
    if (wv >= N) return;
    int beg = off[wv], end = off[wv + 1];
    float sx = 0.f, se = 0.f;
    int i = beg;
    for (; i + 4 <= end; i += 4) {
        int2 p0 = elist[i + 0];
        int2 p1 = elist[i + 1];
        int2 p2 = elist[i + 2];
        int2 p3 = elist[i + 3];
        float x0 = x[(size_t)p0.x * 64 + lane];
        float x1 = x[(size_t)p1.x * 64 + lane];
        float x2 = x[(size_t)p2.x * 64 + lane];
        float x3 = x[(size_t)p3.x * 64 + lane];
        float e0 = 0.f, e1 = 0.f, e2 = 0.f, e3 = 0.f;
        if (lane < 32) {
            e0 = ea[(size_t)p0.y * 32 + lane];
            e1 = ea[(size_t)p1.y * 32 + lane];
            e2 = ea[(size_t)p2.y * 32 + lane];
            e3 = ea[(size_t)p3.y * 32 + lane];
        }
        sx += (x0 + x1) + (x2 + x3);
        se += (e0 + e1) + (e2 + e3);
    }
    for (; i < end; i++) {
        int2 p = elist[i];
        sx += x[(size_t)p.x * 64 + lane];
        if (lane < 32) se += ea[(size_t)p.y * 32 + lane];
    }
    S1[(size_t)wv * 64 + lane] = sx;
    if (lane < 32) EA[(size_t)wv * 32 + lane] = se;
}

// ---------------------------------------------------------------------------
// Layer-2 aggregate: one wave per node, 4-way unrolled gather of g2 (64f).
// ---------------------------------------------------------------------------
__global__ __launch_bounds__(256) void agg2_kernel(const float* __restrict__ g2,
                                                   const int2* __restrict__ elist,
                                                   const int* __restrict__ off,
                                                   float* __restrict__ S2g, int N)
{
    int wv = (blockIdx.x * blockDim.x + threadIdx.x) >> 6;
    int lane = threadIdx.x & 63;
    if (wv >= N) return;
    int beg = off[wv], end = off[wv + 1];
    float sg = 0.f;
    int i = beg;
    for (; i + 4 <= end; i += 4) {
        int2 p0 = elist[i + 0];
        int2 p1 = elist[i + 1];
        int2 p2 = elist[i + 2];
        int2 p3 = elist[i + 3];
        float g0 = g2[(size_t)p0.x * 64 + lane];
        float g1 = g2[(size_t)p1.x * 64 + lane];
        float g3a = g2[(size_t)p2.x * 64 + lane];
        float g3b = g2[(size_t)p3.x * 64 + lane];
        sg += (g0 + g1) + (g3a + g3b);
    }
    for (; i < end; i++) {
        int2 p = elist[i];
        sg += g2[(size_t)p.x * 64 + lane];
    }
    S2g[(size_t)wv * 64 + lane] = sg;
}

// ---------------------------------------------------------------------------
// Layer-1 node kernel + fused g2 = h1 @ Wmsg2[0:128]; float4 LDS reads.
// ---------------------------------------------------------------------------
#define NPB1 16
__global__ __launch_bounds__(128) void node1_kernel(
    const float* __restrict__ x,
    const float* __restrict__ S1,
    const float* __restrict__ EA,
    const int*   __restrict__ deg,
    const float* __restrict__ Wmsg,   // [96][128] rows: 0-63 x-part, 64-95 ea-part
    const float* __restrict__ bmsg,   // [128]
    const float* __restrict__ Wapp,   // [192][128] rows: 0-63 x, 64-191 aggr
    const float* __restrict__ bapp,   // [128]
    const float* __restrict__ Wm2h,   // Wmsg2 rows 0..127 -> [128][64]
    float* __restrict__ h1,
    float* __restrict__ g2,
    int N)
{
    __shared__ __align__(16) float sF[NPB1][96];    // [S1 | EA] per node
    __shared__ __align__(16) float sX[NPB1][64];
    __shared__ __align__(16) float sAgg[NPB1][128];
    __shared__ __align__(16) float sH[NPB1][128];
    __shared__ float sCnt[NPB1];

    int j = threadIdx.x;              // 0..127
    int base = blockIdx.x * NPB1;

    for (int t = j; t < NPB1 * 64; t += 128) {
        int n = t >> 6, k = t & 63;
        int v = base + n;
        sF[n][k] = (v < N) ? S1[(size_t)v * 64 + k] : 0.f;
        sX[n][k] = (v < N) ? x[(size_t)v * 64 + k] : 0.f;
    }
    for (int t = j; t < NPB1 * 32; t += 128) {
        int n = t >> 5, k = t & 31;
        int v = base + n;
        sF[n][64 + k] = (v < N) ? EA[(size_t)v * 32 + k] : 0.f;
    }
    if (j < NPB1) {
        int v = base + j;
        sCnt[j] = (v < N) ? (float)deg[v] : 0.f;
    }
    __syncthreads();

    float acc[NPB1];
#pragma unroll
    for (int n = 0; n < NPB1; n++) acc[n] = 0.f;

    for (int k = 0; k < 96; k += 4) {
        float w0 = Wmsg[(k + 0) * 128 + j];
        float w1 = Wmsg[(k + 1) * 128 + j];
        float w2 = Wmsg[(k + 2) * 128 + j];
        float w3 = Wmsg[(k + 3) * 128 + j];
#pragma unroll
        for (int n = 0; n < NPB1; n++) {
            float4 f = *(const float4*)&sF[n][k];
            acc[n] += f.x * w0 + f.y * w1 + f.z * w2 + f.w * w3;
        }
    }
    float bm = bmsg[j];
#pragma unroll
    for (int n = 0; n < NPB1; n++) {
        float c = sCnt[n];
        sAgg[n][j] = (acc[n] + c * bm) / fmaxf(c, 1.0f);
    }
    __syncthreads();

#pragma unroll
    for (int n = 0; n < NPB1; n++) acc[n] = 0.f;
    for (int k = 0; k < 64; k += 4) {
        float w0 = Wapp[(k + 0) * 128 + j];
        float w1 = Wapp[(k + 1) * 128 + j];
        float w2 = Wapp[(k + 2) * 128 + j];
        float w3 = Wapp[(k + 3) * 128 + j];
#pragma unroll
        for (int n = 0; n < NPB1; n++) {
            float4 f = *(const float4*)&sX[n][k];
            acc[n] += f.x * w0 + f.y * w1 + f.z * w2 + f.w * w3;
        }
    }
    for (int k = 0; k < 128; k += 4) {
        float w0 = Wapp[(64 + k + 0) * 128 + j];
        float w1 = Wapp[(64 + k + 1) * 128 + j];
        float w2 = Wapp[(64 + k + 2) * 128 + j];
        float w3 = Wapp[(64 + k + 3) * 128 + j];
#pragma unroll
        for (int n = 0; n < NPB1; n++) {
            float4 f = *(const float4*)&sAgg[n][k];
            acc[n] += f.x * w0 + f.y * w1 + f.z * w2 + f.w * w3;
        }
    }
    float ba = bapp[j];
#pragma unroll
    for (int n = 0; n < NPB1; n++) {
        float hv = fmaxf(acc[n] + ba, 0.f);
        sH[n][j] = hv;
        int v = base + n;
        if (v < N) h1[(size_t)v * 128 + j] = hv;
    }
    __syncthreads();

    // g2 = h1 @ Wm2h  (128 -> 64). threads j<64: nodes 0..7; j>=64: nodes 8..15
    int col = j & 63;
    int nb = (j >> 6) * 8;
    float ga[8];
#pragma unroll
    for (int n = 0; n < 8; n++) ga[n] = 0.f;
    for (int k = 0; k < 128; k += 4) {
        float w0 = Wm2h[(k + 0) * 64 + col];
        float w1 = Wm2h[(k + 1) * 64 + col];
        float w2 = Wm2h[(k + 2) * 64 + col];
        float w3 = Wm2h[(k + 3) * 64 + col];
#pragma unroll
        for (int n = 0; n < 8; n++) {
            float4 f = *(const float4*)&sH[nb + n][k];
            ga[n] += f.x * w0 + f.y * w1 + f.z * w2 + f.w * w3;
        }
    }
#pragma unroll
    for (int n = 0; n < 8; n++) {
        int v = base + nb + n;
        if (v < N) g2[(size_t)v * 64 + col] = ga[n];
    }
}

// ---------------------------------------------------------------------------
// Layer-2 node kernel: 128 threads, 2 waves; each thread handles 8 nodes.
// aggr2 = (S2g + EA@We2 + cnt*b_msg2)/max(cnt,1)
// out   = relu([h1, aggr2] @ W_app2 + b_app2)
// ---------------------------------------------------------------------------
#define NPB2 16
__global__ __launch_bounds__(128) void node2_kernel(
    const float* __restrict__ h1,
    const float* __restrict__ S2g,
    const float* __restrict__ EA,
    const int*   __restrict__ deg,
    const float* __restrict__ Wme,    // Wmsg2 rows 128..159 -> [32][64]
    const float* __restrict__ bmsg,   // [64]
    const float* __restrict__ Wapp,   // [192][64] rows: 0-127 h, 128-191 aggr
    const float* __restrict__ bapp,   // [64]
    float* __restrict__ out,
    int N)
{
    __shared__ __align__(16) float sEA[NPB2][32];
    __shared__ __align__(16) float sH[NPB2][128];
    __shared__ __align__(16) float sAgg[NPB2][64];
    __shared__ float sCnt[NPB2];

    int t = threadIdx.x;              // 0..127
    int j = t & 63;                   // output column
    int nb = (t >> 6) * 8;            // node sub-block: 0..7 or 8..15
    int base = blockIdx.x * NPB2;

    for (int q = t; q < NPB2 * 128; q += 128) {
        int n = q >> 7, k = q & 127;
        int v = base + n;
        sH[n][k] = (v < N) ? h1[(size_t)v * 128 + k] : 0.f;
    }
    for (int q = t; q < NPB2 * 32; q += 128) {
        int n = q >> 5, k = q & 31;
        int v = base + n;
        sEA[n][k] = (v < N) ? EA[(size_t)v * 32 + k] : 0.f;
    }
    if (t < NPB2) {
        int v = base + t;
        sCnt[t] = (v < N) ? (float)deg[v] : 0.f;
    }
    __syncthreads();

    float acc[8];
#pragma unroll
    for (int n = 0; n < 8; n++) acc[n] = 0.f;

    for (int k = 0; k < 32; k += 4) {
        float w0 = Wme[(k + 0) * 64 + j];
        float w1 = Wme[(k + 1) * 64 + j];
        float w2 = Wme[(k + 2) * 64 + j];
        float w3 = Wme[(k + 3) * 64 + j];
#pragma unroll
        for (int n = 0; n < 8; n++) {
            float4 f = *(const float4*)&sEA[nb + n][k];
            acc[n] += f.x * w0 + f.y * w1 + f.z * w2 + f.w * w3;
        }
    }
    float bm = bmsg[j];
#pragma unroll
    for (int n = 0; n < 8; n++) {
        int v = base + nb + n;
        float sg = (v < N) ? S2g[(size_t)v * 64 + j] : 0.f;
        float c = sCnt[nb + n];
        sAgg[nb + n][j] = (sg + acc[n] + c * bm) / fmaxf(c, 1.0f);
    }
    __syncthreads();

#pragma unroll
    for (int n = 0; n < 8; n++) acc[n] = 0.f;
    for (int k = 0; k < 128; k += 4) {
        float w0 = Wapp[(k + 0) * 64 + j];
        float w1 = Wapp[(k + 1) * 64 + j];
        float w2 = Wapp[(k + 2) * 64 + j];
        float w3 = Wapp[(k + 3) * 64 + j];
#pragma unroll
        for (int n = 0; n < 8; n++) {
            float4 f = *(const float4*)&sH[nb + n][k];
            acc[n] += f.x * w0 + f.y * w1 + f.z * w2 + f.w * w3;
        }
    }
    for (int k = 0; k < 64; k += 4) {
        float w0 = Wapp[(128 + k + 0) * 64 + j];
        float w1 = Wapp[(128 + k + 1) * 64 + j];
        float w2 = Wapp[(128 + k + 2) * 64 + j];
        float w3 = Wapp[(128 + k + 3) * 64 + j];
#pragma unroll
        for (int n = 0; n < 8; n++) {
            float4 f = *(const float4*)&sAgg[nb + n][k];
            acc[n] += f.x * w0 + f.y * w1 + f.z * w2 + f.w * w3;
        }
    }
    float ba = bapp[j];
#pragma unroll
    for (int n = 0; n < 8; n++) {
        int v = base + nb + n;
        if (v < N) out[(size_t)v * 64 + j] = fmaxf(acc[n] + ba, 0.f);
    }
}

// ---------------------------------------------------------------------------
extern "C" void kernel_launch(void* const* d_in, const int* in_sizes, int n_in,
                              void* d_out, int out_size, void* d_ws, size_t ws_size,
                              hipStream_t stream) {
    const float* x      = (const float*)d_in[0];
    const int*   ei     = (const int*)d_in[1];
    const float* ea     = (const float*)d_in[2];
    const float* Wmsg1  = (const float*)d_in[3];
    const float* bmsg1  = (const float*)d_in[4];
    const float* Wapp1  = (const float*)d_in[5];
    const float* bapp1  = (const float*)d_in[6];
    const float* Wmsg2  = (const float*)d_in[7];
    const float* bmsg2  = (const float*)d_in[8];
    const float* Wapp2  = (const float*)d_in[9];
    const float* bapp2  = (const float*)d_in[10];

    const int N = in_sizes[0] / 64;      // 50000
    const int E = in_sizes[1] / 2;       // 800000
    const int NCH = (N + SCAN_CHUNK - 1) / SCAN_CHUNK;   // 49
    const int* src = ei;
    const int* dst = ei + E;

    // Workspace layout (256B-aligned slices)
    uint8_t* p = (uint8_t*)d_ws;
    auto alloc = [&](size_t bytes) -> void* {
        void* r = (void*)p;
        p += (bytes + 255) & ~(size_t)255;
        return r;
    };
    int*   deg    = (int*)alloc((size_t)N * 4);
    int*   off    = (int*)alloc((size_t)(N + 1) * 4);
    int*   cursor = (int*)alloc((size_t)N * 4);
    int*   part   = (int*)alloc((size_t)NCH * 4);
    int2*  elist  = (int2*)alloc((size_t)E * 8);
    float* S1     = (float*)alloc((size_t)N * 64 * 4);  // reused as S2g
    float* EA     = (float*)alloc((size_t)N * 32 * 4);
    float* h1     = (float*)alloc((size_t)N * 128 * 4);
    float* g2     = (float*)alloc((size_t)N * 64 * 4);
    float* S2g    = S1;   // safe: S1 consumed by node1 before agg2 writes S2g

    hipMemsetAsync(deg, 0, (size_t)N * 4, stream);

    // CSR build
    hist_kernel<<<(E + 255) / 256, 256, 0, stream>>>(dst, deg, E);
    scanA_kernel<<<NCH, 256, 0, stream>>>(deg, part, N);
    scanB_kernel<<<1, 64, 0, stream>>>(part, off + N, NCH);
    scanC_kernel<<<NCH, SCAN_CHUNK, 0, stream>>>(deg, part, off, cursor, N);
    fill_kernel<<<(E + 255) / 256, 256, 0, stream>>>(src, dst, cursor, elist, E);

    // Layer 1
    agg1_kernel<<<(N + 3) / 4, 256, 0, stream>>>(x, ea, elist, off, S1, EA, N);
    node1_kernel<<<(N + NPB1 - 1) / NPB1, 128, 0, stream>>>(
        x, S1, EA, deg, Wmsg1, bmsg1, Wapp1, bapp1, Wmsg2 /*rows 0..127*/,
        h1, g2, N);

    // Layer 2
    agg2_kernel<<<(N + 3) / 4, 256, 0, stream>>>(g2, elist, off, S2g, N);
    node2_kernel<<<(N + NPB2 - 1) / NPB2, 128, 0, stream>>>(
        h1, S2g, EA, deg, Wmsg2 + 128 * 64, bmsg2, Wapp2, bapp2,
        (float*)d_out, N);
}